// Round 1
// baseline (3672.955 us; speedup 1.0000x reference)
//
#include <hip/hip_runtime.h>

constexpr int N_NODES = 50000;
constexpr int N_EDGES = 800000;
constexpr int F_IN  = 512;
constexpr int F_H1  = 256;
constexpr int F_H2  = 128;

__global__ __launch_bounds__(256) void k_set1(float* __restrict__ p, int n) {
  int i = blockIdx.x * 256 + threadIdx.x;
  if (i < n) p[i] = 1.0f;
}

__global__ __launch_bounds__(256) void k_deg(const int* __restrict__ dst,
                                             float* __restrict__ deg, int e) {
  int i = blockIdx.x * 256 + threadIdx.x;
  if (i < e) atomicAdd(&deg[dst[i]], 1.0f);
}

__global__ __launch_bounds__(256) void k_rsqrt(float* __restrict__ p, int n) {
  int i = blockIdx.x * 256 + threadIdx.x;
  if (i < n) p[i] = rsqrtf(p[i]);
}

// C[M,N] = A[M,K] @ B[K,N]. Requires N%64==0, K%16==0; M guarded.
// 256 threads, 64x64 tile, BK=16, 4x4 microtile per thread.
__global__ __launch_bounds__(256) void k_gemm(const float* __restrict__ A,
                                              const float* __restrict__ B,
                                              float* __restrict__ C,
                                              int M, int N, int K) {
  __shared__ float As[16][64];  // As[k][m]
  __shared__ float Bs[16][64];  // Bs[k][n]
  const int tid = threadIdx.x;
  const int tx = tid & 15, ty = tid >> 4;
  const int row0 = blockIdx.x * 64, col0 = blockIdx.y * 64;
  const int am = tid >> 2, ak = (tid & 3) << 2;   // A-tile load coords
  const int bk = tid >> 4, bn = (tid & 15) << 2;  // B-tile load coords
  float acc[4][4] = {};
  for (int k0 = 0; k0 < K; k0 += 16) {
    float4 a4 = make_float4(0.f, 0.f, 0.f, 0.f);
    const int arow = row0 + am;
    if (arow < M) a4 = *(const float4*)&A[(size_t)arow * K + k0 + ak];
    As[ak + 0][am] = a4.x;
    As[ak + 1][am] = a4.y;
    As[ak + 2][am] = a4.z;
    As[ak + 3][am] = a4.w;
    *(float4*)&Bs[bk][bn] = *(const float4*)&B[(size_t)(k0 + bk) * N + col0 + bn];
    __syncthreads();
#pragma unroll
    for (int k = 0; k < 16; ++k) {
      const float4 av = *(const float4*)&As[k][ty << 2];
      const float4 bv = *(const float4*)&Bs[k][tx << 2];
      const float a_[4] = {av.x, av.y, av.z, av.w};
      const float b_[4] = {bv.x, bv.y, bv.z, bv.w};
#pragma unroll
      for (int i = 0; i < 4; ++i)
#pragma unroll
        for (int j = 0; j < 4; ++j) acc[i][j] += a_[i] * b_[j];
    }
    __syncthreads();
  }
#pragma unroll
  for (int i = 0; i < 4; ++i) {
    const int r = row0 + (ty << 2) + i;
    if (r < M)
      *(float4*)&C[(size_t)r * N + col0 + (tx << 2)] =
          make_float4(acc[i][0], acc[i][1], acc[i][2], acc[i][3]);
  }
}

// One wave (64 lanes) per edge; lane covers F/64 consecutive features.
template <int F>
__global__ __launch_bounds__(256) void k_scatter(const float* __restrict__ h,
                                                 const int* __restrict__ src,
                                                 const int* __restrict__ dst,
                                                 const float* __restrict__ dinv,
                                                 float* __restrict__ agg, int e) {
  const int w = (blockIdx.x * 256 + threadIdx.x) >> 6;
  const int lane = threadIdx.x & 63;
  if (w >= e) return;
  const int s = src[w], d = dst[w];
  const float coef = dinv[s] * dinv[d];
  constexpr int V = F / 64;
  const float* hp = h + (size_t)s * F + lane * V;
  float* ap = agg + (size_t)d * F + lane * V;
  if constexpr (V == 4) {
    const float4 v = *(const float4*)hp;
    atomicAdd(&ap[0], v.x * coef);
    atomicAdd(&ap[1], v.y * coef);
    atomicAdd(&ap[2], v.z * coef);
    atomicAdd(&ap[3], v.w * coef);
  } else {
    const float2 v = *(const float2*)hp;
    atomicAdd(&ap[0], v.x * coef);
    atomicAdd(&ap[1], v.y * coef);
  }
}

// out = leaky_relu(agg + dinv^2 * h + bias); one float4 per thread.
template <int F>
__global__ __launch_bounds__(256) void k_epilogue(const float* __restrict__ agg,
                                                  const float* __restrict__ h,
                                                  const float* __restrict__ dinv,
                                                  const float* __restrict__ bias,
                                                  float* __restrict__ outp, int n) {
  constexpr int F4 = F / 4;
  const int gid = blockIdx.x * 256 + threadIdx.x;
  if (gid >= n * F4) return;
  const int node = gid / F4;
  const int f4 = gid - node * F4;
  const float sc = dinv[node] * dinv[node];
  const float4 a = ((const float4*)agg)[gid];
  const float4 hv = ((const float4*)h)[gid];
  const float4 bv = *(const float4*)&bias[f4 * 4];
  float4 r;
  r.x = a.x + sc * hv.x + bv.x;
  r.y = a.y + sc * hv.y + bv.y;
  r.z = a.z + sc * hv.z + bv.z;
  r.w = a.w + sc * hv.w + bv.w;
  r.x = fmaxf(r.x, 0.2f * r.x);
  r.y = fmaxf(r.y, 0.2f * r.y);
  r.z = fmaxf(r.z, 0.2f * r.z);
  r.w = fmaxf(r.w, 0.2f * r.w);
  ((float4*)outp)[gid] = r;
}

extern "C" void kernel_launch(void* const* d_in, const int* in_sizes, int n_in,
                              void* d_out, int out_size, void* d_ws, size_t ws_size,
                              hipStream_t stream) {
  const float* X  = (const float*)d_in[0];
  const int*   ei = (const int*)d_in[1];
  const float* W1 = (const float*)d_in[2];
  const float* b1 = (const float*)d_in[3];
  const float* W2 = (const float*)d_in[4];
  const float* b2 = (const float*)d_in[5];
  float* out = (float*)d_out;
  const int* src = ei;             // edge_index[0]
  const int* dst = ei + N_EDGES;   // edge_index[1]

  float* dinv = (float*)d_ws;                    // N (padded to 50048)
  float* bufA = dinv + 50048;                    // h1 / z1 : N*256
  float* bufB = bufA + (size_t)N_NODES * F_H1;   // agg1 : N*256; later h2|agg2
  float* h2   = bufB;                            // N*128
  float* agg2 = bufB + (size_t)N_NODES * F_H2;   // N*128

  // --- normalization (shared by both layers) ---
  k_set1<<<(N_NODES + 255) / 256, 256, 0, stream>>>(dinv, N_NODES);
  k_deg<<<(N_EDGES + 255) / 256, 256, 0, stream>>>(dst, dinv, N_EDGES);
  k_rsqrt<<<(N_NODES + 255) / 256, 256, 0, stream>>>(dinv, N_NODES);

  // --- layer 1 ---
  hipMemsetAsync(bufB, 0, (size_t)N_NODES * F_H1 * sizeof(float), stream);
  dim3 g1((N_NODES + 63) / 64, F_H1 / 64);
  k_gemm<<<g1, 256, 0, stream>>>(X, W1, bufA, N_NODES, F_H1, F_IN);
  k_scatter<F_H1><<<N_EDGES / 4, 256, 0, stream>>>(bufA, src, dst, dinv, bufB, N_EDGES);
  k_epilogue<F_H1><<<(N_NODES * (F_H1 / 4) + 255) / 256, 256, 0, stream>>>(
      bufB, bufA, dinv, b1, bufA, N_NODES);  // z1 in place into bufA

  // --- layer 2 ---
  dim3 g2((N_NODES + 63) / 64, F_H2 / 64);
  k_gemm<<<g2, 256, 0, stream>>>(bufA, W2, h2, N_NODES, F_H2, F_H1);
  hipMemsetAsync(agg2, 0, (size_t)N_NODES * F_H2 * sizeof(float), stream);
  k_scatter<F_H2><<<N_EDGES / 4, 256, 0, stream>>>(h2, src, dst, dinv, agg2, N_EDGES);
  k_epilogue<F_H2><<<(N_NODES * (F_H2 / 4) + 255) / 256, 256, 0, stream>>>(
      agg2, h2, dinv, b2, out, N_NODES);
}

// Round 2
// 643.197 us; speedup vs baseline: 5.7105x; 5.7105x over previous
//
#include <hip/hip_runtime.h>

constexpr int N_NODES = 50000;
constexpr int N_EDGES = 800000;
constexpr int F_IN  = 512;
constexpr int F_H1  = 256;
constexpr int F_H2  = 128;

// ---------------- CSR build ----------------

__global__ __launch_bounds__(256) void k_count(const int* __restrict__ dst,
                                               int* __restrict__ cnt, int e) {
  int i = blockIdx.x * 256 + threadIdx.x;
  if (i < e) atomicAdd(&cnt[dst[i]], 1);
}

// Single block, 1024 threads: exclusive scan of cnt into rowstart/cursor,
// plus dinv[i] = rsqrt(cnt[i] + 1)  (degree with self-loop).
__global__ __launch_bounds__(1024) void k_scan(const int* __restrict__ cnt,
                                               int* __restrict__ rowstart,
                                               int* __restrict__ cursor,
                                               float* __restrict__ dinv, int n) {
  __shared__ int sm[1024];
  __shared__ int carry_s;
  const int t = threadIdx.x;
  if (t == 0) { carry_s = 0; rowstart[0] = 0; }
  __syncthreads();
  for (int base = 0; base < n; base += 1024) {
    const int idx = base + t;
    int v = (idx < n) ? cnt[idx] : 0;
    if (idx < n) dinv[idx] = rsqrtf((float)v + 1.0f);
    int x = v;
    sm[t] = x;
    __syncthreads();
#pragma unroll
    for (int off = 1; off < 1024; off <<= 1) {
      int y = (t >= off) ? sm[t - off] : 0;
      __syncthreads();
      x += y;
      sm[t] = x;
      __syncthreads();
    }
    const int carry = carry_s;
    if (idx < n) {
      rowstart[idx + 1] = carry + x;       // inclusive, shifted
      cursor[idx] = carry + x - v;         // exclusive start
    }
    __syncthreads();
    if (t == 1023) carry_s = carry + x;
    __syncthreads();
  }
}

__global__ __launch_bounds__(256) void k_fill(const int* __restrict__ src,
                                              const int* __restrict__ dst,
                                              int* __restrict__ cursor,
                                              int* __restrict__ csr_src, int e) {
  int i = blockIdx.x * 256 + threadIdx.x;
  if (i < e) {
    int slot = atomicAdd(&cursor[dst[i]], 1);
    csr_src[slot] = src[i];
  }
}

// ---------------- dense GEMM (f32) ----------------
// C[M,N] = A[M,K] @ B[K,N]. N%64==0, K%16==0; M guarded.
__global__ __launch_bounds__(256) void k_gemm(const float* __restrict__ A,
                                              const float* __restrict__ B,
                                              float* __restrict__ C,
                                              int M, int N, int K) {
  __shared__ float As[16][64];
  __shared__ float Bs[16][64];
  const int tid = threadIdx.x;
  const int tx = tid & 15, ty = tid >> 4;
  const int row0 = blockIdx.x * 64, col0 = blockIdx.y * 64;
  const int am = tid >> 2, ak = (tid & 3) << 2;
  const int bk = tid >> 4, bn = (tid & 15) << 2;
  float acc[4][4] = {};
  for (int k0 = 0; k0 < K; k0 += 16) {
    float4 a4 = make_float4(0.f, 0.f, 0.f, 0.f);
    const int arow = row0 + am;
    if (arow < M) a4 = *(const float4*)&A[(size_t)arow * K + k0 + ak];
    As[ak + 0][am] = a4.x;
    As[ak + 1][am] = a4.y;
    As[ak + 2][am] = a4.z;
    As[ak + 3][am] = a4.w;
    *(float4*)&Bs[bk][bn] = *(const float4*)&B[(size_t)(k0 + bk) * N + col0 + bn];
    __syncthreads();
#pragma unroll
    for (int k = 0; k < 16; ++k) {
      const float4 av = *(const float4*)&As[k][ty << 2];
      const float4 bv = *(const float4*)&Bs[k][tx << 2];
      const float a_[4] = {av.x, av.y, av.z, av.w};
      const float b_[4] = {bv.x, bv.y, bv.z, bv.w};
#pragma unroll
      for (int i = 0; i < 4; ++i)
#pragma unroll
        for (int j = 0; j < 4; ++j) acc[i][j] += a_[i] * b_[j];
    }
    __syncthreads();
  }
#pragma unroll
  for (int i = 0; i < 4; ++i) {
    const int r = row0 + (ty << 2) + i;
    if (r < M)
      *(float4*)&C[(size_t)r * N + col0 + (tx << 2)] =
          make_float4(acc[i][0], acc[i][1], acc[i][2], acc[i][3]);
  }
}

// ---------------- gather aggregation + fused epilogue ----------------
// One wave per node; lane holds F/64 consecutive features in registers.
// out = leaky_relu(sum_in coef*h[src] + dinv^2*h[node] + bias)
template <int F>
__global__ __launch_bounds__(256) void k_agg(const float* __restrict__ h,
                                             const int* __restrict__ rowstart,
                                             const int* __restrict__ csr_src,
                                             const float* __restrict__ dinv,
                                             const float* __restrict__ bias,
                                             float* __restrict__ outp, int n) {
  constexpr int V = F / 64;
  const int node = (blockIdx.x * 256 + threadIdx.x) >> 6;
  const int lane = threadIdx.x & 63;
  if (node >= n) return;
  const float dn = dinv[node];
  const int e0 = rowstart[node], e1 = rowstart[node + 1];
  float acc[V] = {};
  for (int e = e0; e < e1; ++e) {
    const int s = csr_src[e];                 // wave-uniform broadcast load
    const float coef = dn * dinv[s];
    const float* hp = h + (size_t)s * F + lane * V;
    if constexpr (V == 4) {
      const float4 hv = *(const float4*)hp;
      acc[0] += coef * hv.x;
      acc[1] += coef * hv.y;
      acc[2] += coef * hv.z;
      acc[3] += coef * hv.w;
    } else {
      const float2 hv = *(const float2*)hp;
      acc[0] += coef * hv.x;
      acc[1] += coef * hv.y;
    }
  }
  const float sc = dn * dn;
  const float* hp = h + (size_t)node * F + lane * V;
  const float* bp = bias + lane * V;
  float* op = outp + (size_t)node * F + lane * V;
  if constexpr (V == 4) {
    const float4 hv = *(const float4*)hp;
    const float4 bv = *(const float4*)bp;
    float4 r;
    r.x = acc[0] + sc * hv.x + bv.x;
    r.y = acc[1] + sc * hv.y + bv.y;
    r.z = acc[2] + sc * hv.z + bv.z;
    r.w = acc[3] + sc * hv.w + bv.w;
    r.x = fmaxf(r.x, 0.2f * r.x);
    r.y = fmaxf(r.y, 0.2f * r.y);
    r.z = fmaxf(r.z, 0.2f * r.z);
    r.w = fmaxf(r.w, 0.2f * r.w);
    *(float4*)op = r;
  } else {
    const float2 hv = *(const float2*)hp;
    const float2 bv = *(const float2*)bp;
    float2 r;
    r.x = acc[0] + sc * hv.x + bv.x;
    r.y = acc[1] + sc * hv.y + bv.y;
    r.x = fmaxf(r.x, 0.2f * r.x);
    r.y = fmaxf(r.y, 0.2f * r.y);
    *(float2*)op = r;
  }
}

extern "C" void kernel_launch(void* const* d_in, const int* in_sizes, int n_in,
                              void* d_out, int out_size, void* d_ws, size_t ws_size,
                              hipStream_t stream) {
  const float* X  = (const float*)d_in[0];
  const int*   ei = (const int*)d_in[1];
  const float* W1 = (const float*)d_in[2];
  const float* b1 = (const float*)d_in[3];
  const float* W2 = (const float*)d_in[4];
  const float* b2 = (const float*)d_in[5];
  float* out = (float*)d_out;
  const int* src = ei;
  const int* dst = ei + N_EDGES;

  float* dinv = (float*)d_ws;                    // 50048 floats
  float* h1   = dinv + 50048;                    // N*256 (first N*128 reused as h2)
  float* z1   = h1 + (size_t)N_NODES * F_H1;     // N*256
  float* h2   = h1;                              // N*128 (h1 dead after agg1)
  int* ibase    = (int*)(z1 + (size_t)N_NODES * F_H1);
  int* counts   = ibase;                         // N
  int* rowstart = counts + N_NODES;              // N+1
  int* cursor   = rowstart + N_NODES + 1;        // N
  int* csr_src  = cursor + N_NODES;              // E

  // --- CSR + normalization ---
  hipMemsetAsync(counts, 0, N_NODES * sizeof(int), stream);
  k_count<<<(N_EDGES + 255) / 256, 256, 0, stream>>>(dst, counts, N_EDGES);
  k_scan<<<1, 1024, 0, stream>>>(counts, rowstart, cursor, dinv, N_NODES);
  k_fill<<<(N_EDGES + 255) / 256, 256, 0, stream>>>(src, dst, cursor, csr_src, N_EDGES);

  // --- layer 1 ---
  dim3 g1((N_NODES + 63) / 64, F_H1 / 64);
  k_gemm<<<g1, 256, 0, stream>>>(X, W1, h1, N_NODES, F_H1, F_IN);
  k_agg<F_H1><<<(N_NODES + 3) / 4, 256, 0, stream>>>(h1, rowstart, csr_src, dinv, b1,
                                                     z1, N_NODES);

  // --- layer 2 ---
  dim3 g2((N_NODES + 63) / 64, F_H2 / 64);
  k_gemm<<<g2, 256, 0, stream>>>(z1, W2, h2, N_NODES, F_H2, F_H1);
  k_agg<F_H2><<<(N_NODES + 3) / 4, 256, 0, stream>>>(h2, rowstart, csr_src, dinv, b2,
                                                     out, N_NODES);
}

// Round 3
// 462.645 us; speedup vs baseline: 7.9390x; 1.3903x over previous
//
#include <hip/hip_runtime.h>

constexpr int N_NODES = 50000;
constexpr int N_EDGES = 800000;
constexpr int F_IN  = 512;
constexpr int F_H1  = 256;
constexpr int F_H2  = 128;

typedef short  short8  __attribute__((ext_vector_type(8)));
typedef float  f32x4   __attribute__((ext_vector_type(4)));
typedef unsigned short us4 __attribute__((ext_vector_type(4)));

__device__ __forceinline__ unsigned short bf16_rn(float f) {
  unsigned int u = __float_as_uint(f);
  return (unsigned short)((u + 0x7FFFu + ((u >> 16) & 1u)) >> 16);
}
__device__ __forceinline__ float bf16_tof(unsigned short h) {
  return __uint_as_float(((unsigned int)h) << 16);
}

// ---------------- CSR build ----------------

__global__ __launch_bounds__(256) void k_count(const int* __restrict__ dst,
                                               int* __restrict__ cnt, int e) {
  int i = blockIdx.x * 256 + threadIdx.x;
  if (i < e) atomicAdd(&cnt[dst[i]], 1);
}

// Single block, 1024 threads, shuffle-based scan (4 barriers/iter).
__global__ __launch_bounds__(1024) void k_scan(const int* __restrict__ cnt,
                                               int* __restrict__ rowstart,
                                               int* __restrict__ cursor,
                                               float* __restrict__ dinv, int n) {
  __shared__ int wsum[16];
  __shared__ int carry_s;
  const int t = threadIdx.x;
  const int wid = t >> 6, lane = t & 63;
  if (t == 0) { carry_s = 0; rowstart[0] = 0; }
  __syncthreads();
  for (int base = 0; base < n; base += 1024) {
    const int idx = base + t;
    const int v = (idx < n) ? cnt[idx] : 0;
    if (idx < n) dinv[idx] = rsqrtf((float)v + 1.0f);
    int x = v;
#pragma unroll
    for (int off = 1; off < 64; off <<= 1) {
      int y = __shfl_up(x, off);
      if (lane >= off) x += y;
    }
    if (lane == 63) wsum[wid] = x;
    __syncthreads();
    if (wid == 0) {
      int s = (lane < 16) ? wsum[lane] : 0;
#pragma unroll
      for (int off = 1; off < 16; off <<= 1) {
        int y = __shfl_up(s, off);
        if (lane >= off) s += y;
      }
      if (lane < 16) wsum[lane] = s;
    }
    __syncthreads();
    const int carry = carry_s;
    const int woff = (wid == 0) ? 0 : wsum[wid - 1];
    const int inc = carry + woff + x;  // inclusive global prefix
    if (idx < n) {
      rowstart[idx + 1] = inc;
      cursor[idx] = inc - v;
    }
    __syncthreads();
    if (t == 1023) carry_s = inc;
    __syncthreads();
  }
}

__global__ __launch_bounds__(256) void k_fill(const int* __restrict__ src,
                                              const int* __restrict__ dst,
                                              int* __restrict__ cursor,
                                              int* __restrict__ csr_src, int e) {
  int i = blockIdx.x * 256 + threadIdx.x;
  if (i < e) {
    int slot = atomicAdd(&cursor[dst[i]], 1);
    csr_src[slot] = src[i];
  }
}

// ---------------- weight transpose + bf16 split ----------------
// W[K][N] f32 -> Wt_h/Wt_l[N][K] bf16
__global__ __launch_bounds__(256) void k_wsplit(const float* __restrict__ W,
                                                unsigned short* __restrict__ Wth,
                                                unsigned short* __restrict__ Wtl,
                                                int K, int N) {
  int id = blockIdx.x * 256 + threadIdx.x;
  if (id >= K * N) return;
  int n = id / K, k = id - n * K;
  float f = W[(size_t)k * N + n];
  unsigned short h = bf16_rn(f);
  Wth[id] = h;
  Wtl[id] = bf16_rn(f - bf16_tof(h));
}

// ---------------- split-bf16 MFMA GEMM ----------------
// C[M,N] = A[M,K] @ B[K,N], B given pre-transposed+split as Bt[N][K] (hi/lo).
// A either f32 (split in staging) or pre-split bf16 pair.
// 128x128 tile, BK=64, 256 threads = 4 waves (2x2), 4x4 frags of 16x16x32.
template <bool A_IS_F32>
__global__ __launch_bounds__(256) void k_mm(const float* __restrict__ Af,
                                            const unsigned short* __restrict__ Ah,
                                            const unsigned short* __restrict__ Al,
                                            const unsigned short* __restrict__ Bth,
                                            const unsigned short* __restrict__ Btl,
                                            float* __restrict__ C,
                                            int M, int N, int K) {
  __shared__ unsigned short Ah_s[128 * 64];
  __shared__ unsigned short Al_s[128 * 64];
  __shared__ unsigned short Bh_s[128 * 64];
  __shared__ unsigned short Bl_s[128 * 64];
  const int tid = threadIdx.x;
  const int wid = tid >> 6, lane = tid & 63;
  const int wm = wid >> 1, wn = wid & 1;
  const int lr = lane & 15, lg = lane >> 4;
  const int row0 = blockIdx.x * 128, col0 = blockIdx.y * 128;

  f32x4 acc[4][4] = {};

  for (int k0 = 0; k0 < K; k0 += 64) {
    // ---- stage A ----
#pragma unroll
    for (int c = 0; c < 4; ++c) {
      const int i8 = c * 256 + tid;       // 0..1023
      const int r = i8 >> 3, g = i8 & 7;  // row, 16B-granule
      const int gr = row0 + r;
      const int gs = g ^ (r & 7);
      if (A_IS_F32) {
        float4 f0 = make_float4(0.f, 0.f, 0.f, 0.f), f1 = f0;
        if (gr < M) {
          const float* ap = Af + (size_t)gr * K + k0 + g * 8;
          f0 = *(const float4*)ap;
          f1 = *(const float4*)(ap + 4);
        }
        const float fv[8] = {f0.x, f0.y, f0.z, f0.w, f1.x, f1.y, f1.z, f1.w};
        unsigned short hv[8], lv[8];
#pragma unroll
        for (int j = 0; j < 8; ++j) {
          hv[j] = bf16_rn(fv[j]);
          lv[j] = bf16_rn(fv[j] - bf16_tof(hv[j]));
        }
        us4* dh = (us4*)&Ah_s[r * 64 + gs * 8];
        us4* dl = (us4*)&Al_s[r * 64 + gs * 8];
        dh[0] = us4{hv[0], hv[1], hv[2], hv[3]};
        dh[1] = us4{hv[4], hv[5], hv[6], hv[7]};
        dl[0] = us4{lv[0], lv[1], lv[2], lv[3]};
        dl[1] = us4{lv[4], lv[5], lv[6], lv[7]};
      } else {
        short8 h8 = {}, l8 = {};
        if (gr < M) {
          h8 = *(const short8*)&Ah[(size_t)gr * K + k0 + g * 8];
          l8 = *(const short8*)&Al[(size_t)gr * K + k0 + g * 8];
        }
        *(short8*)&Ah_s[r * 64 + gs * 8] = h8;
        *(short8*)&Al_s[r * 64 + gs * 8] = l8;
      }
    }
    // ---- stage B (always pre-split, Bt[N][K]) ----
#pragma unroll
    for (int c = 0; c < 4; ++c) {
      const int i8 = c * 256 + tid;
      const int r = i8 >> 3, g = i8 & 7;
      const int gcol = col0 + r;
      const int gs = g ^ (r & 7);
      *(short8*)&Bh_s[r * 64 + gs * 8] =
          *(const short8*)&Bth[(size_t)gcol * K + k0 + g * 8];
      *(short8*)&Bl_s[r * 64 + gs * 8] =
          *(const short8*)&Btl[(size_t)gcol * K + k0 + g * 8];
    }
    __syncthreads();
    // ---- compute ----
#pragma unroll
    for (int kk = 0; kk < 2; ++kk) {
      short8 ah[4], al[4], bh[4], bl[4];
#pragma unroll
      for (int m = 0; m < 4; ++m) {
        const int r = wm * 64 + m * 16 + lr;
        const int g = kk * 4 + lg;
        const int off = r * 64 + (g ^ (r & 7)) * 8;
        ah[m] = *(const short8*)&Ah_s[off];
        al[m] = *(const short8*)&Al_s[off];
      }
#pragma unroll
      for (int n = 0; n < 4; ++n) {
        const int r = wn * 64 + n * 16 + lr;
        const int g = kk * 4 + lg;
        const int off = r * 64 + (g ^ (r & 7)) * 8;
        bh[n] = *(const short8*)&Bh_s[off];
        bl[n] = *(const short8*)&Bl_s[off];
      }
#pragma unroll
      for (int m = 0; m < 4; ++m)
#pragma unroll
        for (int n = 0; n < 4; ++n)
          acc[m][n] = __builtin_amdgcn_mfma_f32_16x16x32_bf16(ah[m], bh[n],
                                                              acc[m][n], 0, 0, 0);
#pragma unroll
      for (int m = 0; m < 4; ++m)
#pragma unroll
        for (int n = 0; n < 4; ++n) {
          acc[m][n] = __builtin_amdgcn_mfma_f32_16x16x32_bf16(ah[m], bl[n],
                                                              acc[m][n], 0, 0, 0);
          acc[m][n] = __builtin_amdgcn_mfma_f32_16x16x32_bf16(al[m], bh[n],
                                                              acc[m][n], 0, 0, 0);
        }
    }
    __syncthreads();
  }
  // ---- store: C[row][col], row=(lane>>4)*4+j, col=lane&15 within fragment ----
#pragma unroll
  for (int m = 0; m < 4; ++m) {
#pragma unroll
    for (int j = 0; j < 4; ++j) {
      const int row = row0 + wm * 64 + m * 16 + (lane >> 4) * 4 + j;
      if (row < M) {
        float* cp = C + (size_t)row * N + col0 + wn * 64 + (lane & 15);
#pragma unroll
        for (int n = 0; n < 4; ++n) cp[n * 16] = acc[m][n][j];
      }
    }
  }
}

// ---------------- gather aggregation + fused epilogue ----------------
// out = leaky_relu(sum_in coef*h[src] + dinv^2*h[node] + bias)
// SPLIT_OUT: write bf16 hi/lo pair instead of f32 (feeds next GEMM).
template <int F, bool SPLIT_OUT>
__global__ __launch_bounds__(256) void k_agg(const float* __restrict__ h,
                                             const int* __restrict__ rowstart,
                                             const int* __restrict__ csr_src,
                                             const float* __restrict__ dinv,
                                             const float* __restrict__ bias,
                                             float* __restrict__ outp,
                                             unsigned short* __restrict__ outh,
                                             unsigned short* __restrict__ outl,
                                             int n) {
  constexpr int V = F / 64;
  const int node = (blockIdx.x * 256 + threadIdx.x) >> 6;
  const int lane = threadIdx.x & 63;
  if (node >= n) return;
  const float dn = dinv[node];
  const int e0 = rowstart[node], e1 = rowstart[node + 1];
  float acc[V] = {};
  for (int e = e0; e < e1; ++e) {
    const int s = csr_src[e];
    const float coef = dn * dinv[s];
    const float* hp = h + (size_t)s * F + lane * V;
    if constexpr (V == 4) {
      const float4 hv = *(const float4*)hp;
      acc[0] += coef * hv.x;
      acc[1] += coef * hv.y;
      acc[2] += coef * hv.z;
      acc[3] += coef * hv.w;
    } else {
      const float2 hv = *(const float2*)hp;
      acc[0] += coef * hv.x;
      acc[1] += coef * hv.y;
    }
  }
  const float sc = dn * dn;
  const float* hp = h + (size_t)node * F + lane * V;
  const float* bp = bias + lane * V;
  float r[V];
#pragma unroll
  for (int j = 0; j < V; ++j) {
    float t = acc[j] + sc * hp[j] + bp[j];
    r[j] = fmaxf(t, 0.2f * t);
  }
  if constexpr (SPLIT_OUT) {
    unsigned short hh[V], ll[V];
#pragma unroll
    for (int j = 0; j < V; ++j) {
      hh[j] = bf16_rn(r[j]);
      ll[j] = bf16_rn(r[j] - bf16_tof(hh[j]));
    }
    if constexpr (V == 4) {
      *(us4*)&outh[(size_t)node * F + lane * 4] = us4{hh[0], hh[1], hh[2], hh[3]};
      *(us4*)&outl[(size_t)node * F + lane * 4] = us4{ll[0], ll[1], ll[2], ll[3]};
    } else {
#pragma unroll
      for (int j = 0; j < V; ++j) {
        outh[(size_t)node * F + lane * V + j] = hh[j];
        outl[(size_t)node * F + lane * V + j] = ll[j];
      }
    }
  } else {
    float* op = outp + (size_t)node * F + lane * V;
    if constexpr (V == 4) {
      *(float4*)op = make_float4(r[0], r[1], r[2], r[3]);
    } else {
      *(float2*)op = make_float2(r[0], r[1]);
    }
  }
}

extern "C" void kernel_launch(void* const* d_in, const int* in_sizes, int n_in,
                              void* d_out, int out_size, void* d_ws, size_t ws_size,
                              hipStream_t stream) {
  const float* X  = (const float*)d_in[0];
  const int*   ei = (const int*)d_in[1];
  const float* W1 = (const float*)d_in[2];
  const float* b1 = (const float*)d_in[3];
  const float* W2 = (const float*)d_in[4];
  const float* b2 = (const float*)d_in[5];
  float* out = (float*)d_out;
  const int* src = ei;
  const int* dst = ei + N_EDGES;

  // workspace layout (bytes from base):
  char* p = (char*)d_ws;
  float* h1 = (float*)p;                 p += (size_t)N_NODES * F_H1 * 4;  // 51.2MB, reused as h2
  unsigned short* z1h = (unsigned short*)p; p += (size_t)N_NODES * F_H1 * 2;
  unsigned short* z1l = (unsigned short*)p; p += (size_t)N_NODES * F_H1 * 2;
  unsigned short* Wt1h = (unsigned short*)p; p += (size_t)F_IN * F_H1 * 2;
  unsigned short* Wt1l = (unsigned short*)p; p += (size_t)F_IN * F_H1 * 2;
  unsigned short* Wt2h = (unsigned short*)p; p += (size_t)F_H1 * F_H2 * 2;
  unsigned short* Wt2l = (unsigned short*)p; p += (size_t)F_H1 * F_H2 * 2;
  float* dinv = (float*)p;               p += 50048 * 4;
  int* counts = (int*)p;                 p += 50048 * 4;
  int* rowstart = (int*)p;               p += 50056 * 4;
  int* cursor = (int*)p;                 p += 50048 * 4;
  int* csr_src = (int*)p;
  float* h2 = h1;  // h1 dead after agg1

  // --- CSR + normalization ---
  hipMemsetAsync(counts, 0, N_NODES * sizeof(int), stream);
  k_count<<<(N_EDGES + 255) / 256, 256, 0, stream>>>(dst, counts, N_EDGES);
  k_scan<<<1, 1024, 0, stream>>>(counts, rowstart, cursor, dinv, N_NODES);
  k_fill<<<(N_EDGES + 255) / 256, 256, 0, stream>>>(src, dst, cursor, csr_src, N_EDGES);

  // --- weight prep ---
  k_wsplit<<<(F_IN * F_H1 + 255) / 256, 256, 0, stream>>>(W1, Wt1h, Wt1l, F_IN, F_H1);
  k_wsplit<<<(F_H1 * F_H2 + 255) / 256, 256, 0, stream>>>(W2, Wt2h, Wt2l, F_H1, F_H2);

  // --- layer 1: h1 = X @ W1 (split in-kernel) ---
  dim3 g1((N_NODES + 127) / 128, F_H1 / 128);
  k_mm<true><<<g1, 256, 0, stream>>>(X, nullptr, nullptr, Wt1h, Wt1l, h1,
                                     N_NODES, F_H1, F_IN);
  k_agg<F_H1, true><<<(N_NODES + 3) / 4, 256, 0, stream>>>(
      h1, rowstart, csr_src, dinv, b1, nullptr, z1h, z1l, N_NODES);

  // --- layer 2: h2 = z1 @ W2 (pre-split A) ---
  dim3 g2((N_NODES + 127) / 128, F_H2 / 128);
  k_mm<false><<<g2, 256, 0, stream>>>(nullptr, z1h, z1l, Wt2h, Wt2l, h2,
                                      N_NODES, F_H2, F_H1);
  k_agg<F_H2, false><<<(N_NODES + 3) / 4, 256, 0, stream>>>(
      h2, rowstart, csr_src, dinv, b2, out, nullptr, nullptr, N_NODES);
}

// Round 4
// 417.634 us; speedup vs baseline: 8.7947x; 1.1078x over previous
//
#include <hip/hip_runtime.h>

constexpr int N_NODES = 50000;
constexpr int N_EDGES = 800000;
constexpr int F_IN  = 512;
constexpr int F_H1  = 256;
constexpr int F_H2  = 128;

typedef short  short8  __attribute__((ext_vector_type(8)));
typedef float  f32x4   __attribute__((ext_vector_type(4)));
typedef unsigned short us4 __attribute__((ext_vector_type(4)));

__device__ __forceinline__ unsigned short bf16_rn(float f) {
  unsigned int u = __float_as_uint(f);
  return (unsigned short)((u + 0x7FFFu + ((u >> 16) & 1u)) >> 16);
}
__device__ __forceinline__ float bf16_tof(unsigned short h) {
  return __uint_as_float(((unsigned int)h) << 16);
}

// ---------------- CSR build ----------------

__global__ __launch_bounds__(256) void k_count(const int* __restrict__ dst,
                                               int* __restrict__ cnt, int e) {
  int i = blockIdx.x * 256 + threadIdx.x;
  if (i < e) atomicAdd(&cnt[dst[i]], 1);
}

// Single block, 1024 threads, shuffle-based scan.
__global__ __launch_bounds__(1024) void k_scan(const int* __restrict__ cnt,
                                               int* __restrict__ rowstart,
                                               int* __restrict__ cursor,
                                               float* __restrict__ dinv, int n) {
  __shared__ int wsum[16];
  __shared__ int carry_s;
  const int t = threadIdx.x;
  const int wid = t >> 6, lane = t & 63;
  if (t == 0) { carry_s = 0; rowstart[0] = 0; }
  __syncthreads();
  for (int base = 0; base < n; base += 1024) {
    const int idx = base + t;
    const int v = (idx < n) ? cnt[idx] : 0;
    if (idx < n) dinv[idx] = rsqrtf((float)v + 1.0f);
    int x = v;
#pragma unroll
    for (int off = 1; off < 64; off <<= 1) {
      int y = __shfl_up(x, off);
      if (lane >= off) x += y;
    }
    if (lane == 63) wsum[wid] = x;
    __syncthreads();
    if (wid == 0) {
      int s = (lane < 16) ? wsum[lane] : 0;
#pragma unroll
      for (int off = 1; off < 16; off <<= 1) {
        int y = __shfl_up(s, off);
        if (lane >= off) s += y;
      }
      if (lane < 16) wsum[lane] = s;
    }
    __syncthreads();
    const int carry = carry_s;
    const int woff = (wid == 0) ? 0 : wsum[wid - 1];
    const int inc = carry + woff + x;
    if (idx < n) {
      rowstart[idx + 1] = inc;
      cursor[idx] = inc - v;
    }
    __syncthreads();
    if (t == 1023) carry_s = inc;
    __syncthreads();
  }
}

// Fill packed CSR: (src, coef) with coef = dinv[src]*dinv[dst].
__global__ __launch_bounds__(256) void k_fill(const int* __restrict__ src,
                                              const int* __restrict__ dst,
                                              int* __restrict__ cursor,
                                              const float* __restrict__ dinv,
                                              int2* __restrict__ csr, int e) {
  int i = blockIdx.x * 256 + threadIdx.x;
  if (i < e) {
    const int s = src[i], d = dst[i];
    int slot = atomicAdd(&cursor[d], 1);
    csr[slot] = make_int2(s, __float_as_int(dinv[s] * dinv[d]));
  }
}

// ---------------- weight transpose + bf16 split ----------------
__global__ __launch_bounds__(256) void k_wsplit(const float* __restrict__ W,
                                                unsigned short* __restrict__ Wth,
                                                unsigned short* __restrict__ Wtl,
                                                int K, int N) {
  int id = blockIdx.x * 256 + threadIdx.x;
  if (id >= K * N) return;
  int n = id / K, k = id - n * K;
  float f = W[(size_t)k * N + n];
  unsigned short h = bf16_rn(f);
  Wth[id] = h;
  Wtl[id] = bf16_rn(f - bf16_tof(h));
}

// ---------------- split-bf16 MFMA GEMM ----------------
// C[M,N] = A[M,K] @ B[K,N], B pre-transposed+split as Bt[N][K] (hi/lo).
// 128x128 tile, BK=64, 256 threads = 4 waves (2x2), 4x4 frags of 16x16x32.
template <bool A_IS_F32>
__global__ __launch_bounds__(256) void k_mm(const float* __restrict__ Af,
                                            const unsigned short* __restrict__ Ah,
                                            const unsigned short* __restrict__ Al,
                                            const unsigned short* __restrict__ Bth,
                                            const unsigned short* __restrict__ Btl,
                                            float* __restrict__ C,
                                            int M, int N, int K) {
  __shared__ unsigned short Ah_s[128 * 64];
  __shared__ unsigned short Al_s[128 * 64];
  __shared__ unsigned short Bh_s[128 * 64];
  __shared__ unsigned short Bl_s[128 * 64];
  const int tid = threadIdx.x;
  const int wid = tid >> 6, lane = tid & 63;
  const int wm = wid >> 1, wn = wid & 1;
  const int lr = lane & 15, lg = lane >> 4;
  const int row0 = blockIdx.x * 128, col0 = blockIdx.y * 128;

  f32x4 acc[4][4] = {};

  for (int k0 = 0; k0 < K; k0 += 64) {
#pragma unroll
    for (int c = 0; c < 4; ++c) {
      const int i8 = c * 256 + tid;
      const int r = i8 >> 3, g = i8 & 7;
      const int gr = row0 + r;
      const int gs = g ^ (r & 7);
      if (A_IS_F32) {
        float4 f0 = make_float4(0.f, 0.f, 0.f, 0.f), f1 = f0;
        if (gr < M) {
          const float* ap = Af + (size_t)gr * K + k0 + g * 8;
          f0 = *(const float4*)ap;
          f1 = *(const float4*)(ap + 4);
        }
        const float fv[8] = {f0.x, f0.y, f0.z, f0.w, f1.x, f1.y, f1.z, f1.w};
        unsigned short hv[8], lv[8];
#pragma unroll
        for (int j = 0; j < 8; ++j) {
          hv[j] = bf16_rn(fv[j]);
          lv[j] = bf16_rn(fv[j] - bf16_tof(hv[j]));
        }
        us4* dh = (us4*)&Ah_s[r * 64 + gs * 8];
        us4* dl = (us4*)&Al_s[r * 64 + gs * 8];
        dh[0] = us4{hv[0], hv[1], hv[2], hv[3]};
        dh[1] = us4{hv[4], hv[5], hv[6], hv[7]};
        dl[0] = us4{lv[0], lv[1], lv[2], lv[3]};
        dl[1] = us4{lv[4], lv[5], lv[6], lv[7]};
      } else {
        short8 h8 = {}, l8 = {};
        if (gr < M) {
          h8 = *(const short8*)&Ah[(size_t)gr * K + k0 + g * 8];
          l8 = *(const short8*)&Al[(size_t)gr * K + k0 + g * 8];
        }
        *(short8*)&Ah_s[r * 64 + gs * 8] = h8;
        *(short8*)&Al_s[r * 64 + gs * 8] = l8;
      }
    }
#pragma unroll
    for (int c = 0; c < 4; ++c) {
      const int i8 = c * 256 + tid;
      const int r = i8 >> 3, g = i8 & 7;
      const int gcol = col0 + r;
      const int gs = g ^ (r & 7);
      *(short8*)&Bh_s[r * 64 + gs * 8] =
          *(const short8*)&Bth[(size_t)gcol * K + k0 + g * 8];
      *(short8*)&Bl_s[r * 64 + gs * 8] =
          *(const short8*)&Btl[(size_t)gcol * K + k0 + g * 8];
    }
    __syncthreads();
#pragma unroll
    for (int kk = 0; kk < 2; ++kk) {
      short8 ah[4], al[4], bh[4], bl[4];
#pragma unroll
      for (int m = 0; m < 4; ++m) {
        const int r = wm * 64 + m * 16 + lr;
        const int g = kk * 4 + lg;
        const int off = r * 64 + (g ^ (r & 7)) * 8;
        ah[m] = *(const short8*)&Ah_s[off];
        al[m] = *(const short8*)&Al_s[off];
      }
#pragma unroll
      for (int n = 0; n < 4; ++n) {
        const int r = wn * 64 + n * 16 + lr;
        const int g = kk * 4 + lg;
        const int off = r * 64 + (g ^ (r & 7)) * 8;
        bh[n] = *(const short8*)&Bh_s[off];
        bl[n] = *(const short8*)&Bl_s[off];
      }
#pragma unroll
      for (int m = 0; m < 4; ++m)
#pragma unroll
        for (int n = 0; n < 4; ++n)
          acc[m][n] = __builtin_amdgcn_mfma_f32_16x16x32_bf16(ah[m], bh[n],
                                                              acc[m][n], 0, 0, 0);
#pragma unroll
      for (int m = 0; m < 4; ++m)
#pragma unroll
        for (int n = 0; n < 4; ++n) {
          acc[m][n] = __builtin_amdgcn_mfma_f32_16x16x32_bf16(ah[m], bl[n],
                                                              acc[m][n], 0, 0, 0);
          acc[m][n] = __builtin_amdgcn_mfma_f32_16x16x32_bf16(al[m], bh[n],
                                                              acc[m][n], 0, 0, 0);
        }
    }
    __syncthreads();
  }
#pragma unroll
  for (int m = 0; m < 4; ++m) {
#pragma unroll
    for (int j = 0; j < 4; ++j) {
      const int row = row0 + wm * 64 + m * 16 + (lane >> 4) * 4 + j;
      if (row < M) {
        float* cp = C + (size_t)row * N + col0 + wn * 64 + (lane & 15);
#pragma unroll
        for (int n = 0; n < 4; ++n) cp[n * 16] = acc[m][n][j];
      }
    }
  }
}

// ---------------- gather aggregation + fused epilogue ----------------
// One wave per node; 4-wide edge unroll for memory-level parallelism.
// out = leaky_relu(sum_in coef*h[src] + dinv^2*h[node] + bias)
template <int F, bool SPLIT_OUT>
__global__ __launch_bounds__(256) void k_agg(const float* __restrict__ h,
                                             const int* __restrict__ rowstart,
                                             const int2* __restrict__ csr,
                                             const float* __restrict__ dinv,
                                             const float* __restrict__ bias,
                                             float* __restrict__ outp,
                                             unsigned short* __restrict__ outh,
                                             unsigned short* __restrict__ outl,
                                             int n) {
  constexpr int V = F / 64;
  const int node = (blockIdx.x * 256 + threadIdx.x) >> 6;
  const int lane = threadIdx.x & 63;
  if (node >= n) return;
  const float dn = dinv[node];
  const int e0 = rowstart[node];
  const int cnt = rowstart[node + 1] - e0;
  const int2* cp = csr + e0;
  float acc[V] = {};
  int i = 0;
  if constexpr (V == 4) {
    for (; i + 4 <= cnt; i += 4) {
      const int2 p0 = cp[i], p1 = cp[i + 1], p2 = cp[i + 2], p3 = cp[i + 3];
      const float4 v0 = *(const float4*)(h + (size_t)p0.x * F + lane * 4);
      const float4 v1 = *(const float4*)(h + (size_t)p1.x * F + lane * 4);
      const float4 v2 = *(const float4*)(h + (size_t)p2.x * F + lane * 4);
      const float4 v3 = *(const float4*)(h + (size_t)p3.x * F + lane * 4);
      const float c0 = __int_as_float(p0.y), c1 = __int_as_float(p1.y);
      const float c2 = __int_as_float(p2.y), c3 = __int_as_float(p3.y);
      acc[0] += c0 * v0.x + c1 * v1.x + c2 * v2.x + c3 * v3.x;
      acc[1] += c0 * v0.y + c1 * v1.y + c2 * v2.y + c3 * v3.y;
      acc[2] += c0 * v0.z + c1 * v1.z + c2 * v2.z + c3 * v3.z;
      acc[3] += c0 * v0.w + c1 * v1.w + c2 * v2.w + c3 * v3.w;
    }
    for (; i < cnt; ++i) {
      const int2 p = cp[i];
      const float c = __int_as_float(p.y);
      const float4 v = *(const float4*)(h + (size_t)p.x * F + lane * 4);
      acc[0] += c * v.x;
      acc[1] += c * v.y;
      acc[2] += c * v.z;
      acc[3] += c * v.w;
    }
  } else {
    for (; i + 4 <= cnt; i += 4) {
      const int2 p0 = cp[i], p1 = cp[i + 1], p2 = cp[i + 2], p3 = cp[i + 3];
      const float2 v0 = *(const float2*)(h + (size_t)p0.x * F + lane * 2);
      const float2 v1 = *(const float2*)(h + (size_t)p1.x * F + lane * 2);
      const float2 v2 = *(const float2*)(h + (size_t)p2.x * F + lane * 2);
      const float2 v3 = *(const float2*)(h + (size_t)p3.x * F + lane * 2);
      const float c0 = __int_as_float(p0.y), c1 = __int_as_float(p1.y);
      const float c2 = __int_as_float(p2.y), c3 = __int_as_float(p3.y);
      acc[0] += c0 * v0.x + c1 * v1.x + c2 * v2.x + c3 * v3.x;
      acc[1] += c0 * v0.y + c1 * v1.y + c2 * v2.y + c3 * v3.y;
    }
    for (; i < cnt; ++i) {
      const int2 p = cp[i];
      const float c = __int_as_float(p.y);
      const float2 v = *(const float2*)(h + (size_t)p.x * F + lane * 2);
      acc[0] += c * v.x;
      acc[1] += c * v.y;
    }
  }
  const float sc = dn * dn;
  const float* hp = h + (size_t)node * F + lane * V;
  const float* bp = bias + lane * V;
  float r[V];
#pragma unroll
  for (int j = 0; j < V; ++j) {
    float t = acc[j] + sc * hp[j] + bp[j];
    r[j] = fmaxf(t, 0.2f * t);
  }
  if constexpr (SPLIT_OUT) {
    unsigned short hh[V], ll[V];
#pragma unroll
    for (int j = 0; j < V; ++j) {
      hh[j] = bf16_rn(r[j]);
      ll[j] = bf16_rn(r[j] - bf16_tof(hh[j]));
    }
    if constexpr (V == 4) {
      *(us4*)&outh[(size_t)node * F + lane * 4] = us4{hh[0], hh[1], hh[2], hh[3]};
      *(us4*)&outl[(size_t)node * F + lane * 4] = us4{ll[0], ll[1], ll[2], ll[3]};
    } else {
#pragma unroll
      for (int j = 0; j < V; ++j) {
        outh[(size_t)node * F + lane * V + j] = hh[j];
        outl[(size_t)node * F + lane * V + j] = ll[j];
      }
    }
  } else {
    float* op = outp + (size_t)node * F + lane * V;
    if constexpr (V == 4) {
      *(float4*)op = make_float4(r[0], r[1], r[2], r[3]);
    } else {
      *(float2*)op = make_float2(r[0], r[1]);
    }
  }
}

extern "C" void kernel_launch(void* const* d_in, const int* in_sizes, int n_in,
                              void* d_out, int out_size, void* d_ws, size_t ws_size,
                              hipStream_t stream) {
  const float* X  = (const float*)d_in[0];
  const int*   ei = (const int*)d_in[1];
  const float* W1 = (const float*)d_in[2];
  const float* b1 = (const float*)d_in[3];
  const float* W2 = (const float*)d_in[4];
  const float* b2 = (const float*)d_in[5];
  float* out = (float*)d_out;
  const int* src = ei;
  const int* dst = ei + N_EDGES;

  char* p = (char*)d_ws;
  float* h1 = (float*)p;                 p += (size_t)N_NODES * F_H1 * 4;
  unsigned short* z1h = (unsigned short*)p; p += (size_t)N_NODES * F_H1 * 2;
  unsigned short* z1l = (unsigned short*)p; p += (size_t)N_NODES * F_H1 * 2;
  unsigned short* Wt1h = (unsigned short*)p; p += (size_t)F_IN * F_H1 * 2;
  unsigned short* Wt1l = (unsigned short*)p; p += (size_t)F_IN * F_H1 * 2;
  unsigned short* Wt2h = (unsigned short*)p; p += (size_t)F_H1 * F_H2 * 2;
  unsigned short* Wt2l = (unsigned short*)p; p += (size_t)F_H1 * F_H2 * 2;
  float* dinv = (float*)p;               p += 50048 * 4;
  int* counts = (int*)p;                 p += 50048 * 4;
  int* rowstart = (int*)p;               p += 50056 * 4;
  int* cursor = (int*)p;                 p += 50048 * 4;
  int2* csr = (int2*)p;                  p += (size_t)N_EDGES * 8;
  float* h2 = h1;  // h1 dead after agg1

  // --- CSR + normalization ---
  hipMemsetAsync(counts, 0, N_NODES * sizeof(int), stream);
  k_count<<<(N_EDGES + 255) / 256, 256, 0, stream>>>(dst, counts, N_EDGES);
  k_scan<<<1, 1024, 0, stream>>>(counts, rowstart, cursor, dinv, N_NODES);
  k_fill<<<(N_EDGES + 255) / 256, 256, 0, stream>>>(src, dst, cursor, dinv, csr,
                                                    N_EDGES);

  // --- weight prep ---
  k_wsplit<<<(F_IN * F_H1 + 255) / 256, 256, 0, stream>>>(W1, Wt1h, Wt1l, F_IN, F_H1);
  k_wsplit<<<(F_H1 * F_H2 + 255) / 256, 256, 0, stream>>>(W2, Wt2h, Wt2l, F_H1, F_H2);

  // --- layer 1 ---
  dim3 g1((N_NODES + 127) / 128, F_H1 / 128);
  k_mm<true><<<g1, 256, 0, stream>>>(X, nullptr, nullptr, Wt1h, Wt1l, h1,
                                     N_NODES, F_H1, F_IN);
  k_agg<F_H1, true><<<(N_NODES + 3) / 4, 256, 0, stream>>>(
      h1, rowstart, csr, dinv, b1, nullptr, z1h, z1l, N_NODES);

  // --- layer 2 ---
  dim3 g2((N_NODES + 127) / 128, F_H2 / 128);
  k_mm<false><<<g2, 256, 0, stream>>>(nullptr, z1h, z1l, Wt2h, Wt2l, h2,
                                      N_NODES, F_H2, F_H1);
  k_agg<F_H2, false><<<(N_NODES + 3) / 4, 256, 0, stream>>>(
      h2, rowstart, csr, dinv, b2, out, nullptr, nullptr, N_NODES);
}

// Round 5
// 352.222 us; speedup vs baseline: 10.4279x; 1.1857x over previous
//
#include <hip/hip_runtime.h>

constexpr int N_NODES = 50000;
constexpr int N_EDGES = 800000;
constexpr int F_IN  = 512;
constexpr int F_H1  = 256;
constexpr int F_H2  = 128;

typedef short  short8  __attribute__((ext_vector_type(8)));
typedef float  f32x4   __attribute__((ext_vector_type(4)));
typedef unsigned short us4 __attribute__((ext_vector_type(4)));

__device__ __forceinline__ unsigned short bf16_rn(float f) {
  unsigned int u = __float_as_uint(f);
  return (unsigned short)((u + 0x7FFFu + ((u >> 16) & 1u)) >> 16);
}
__device__ __forceinline__ float bf16_tof(unsigned short h) {
  return __uint_as_float(((unsigned int)h) << 16);
}

// ---------------- CSR build ----------------

__global__ __launch_bounds__(256) void k_count(const int* __restrict__ dst,
                                               int* __restrict__ cnt, int e) {
  int i = blockIdx.x * 256 + threadIdx.x;
  if (i < e) atomicAdd(&cnt[dst[i]], 1);
}

// Single block, 1024 threads, 4 elems/thread, shuffle-based scan.
__global__ __launch_bounds__(1024) void k_scan(const int* __restrict__ cnt,
                                               int* __restrict__ rowstart,
                                               int* __restrict__ cursor,
                                               float* __restrict__ dinv, int n) {
  __shared__ int wsum[16];
  __shared__ int carry_s;
  const int t = threadIdx.x;
  const int wid = t >> 6, lane = t & 63;
  if (t == 0) { carry_s = 0; rowstart[0] = 0; }
  __syncthreads();
  for (int base = 0; base < n; base += 4096) {
    const int i0 = base + t * 4;
    int v[4];
    if (i0 + 4 <= n) {
      const int4 v4 = *(const int4*)&cnt[i0];
      v[0] = v4.x; v[1] = v4.y; v[2] = v4.z; v[3] = v4.w;
    } else {
#pragma unroll
      for (int j = 0; j < 4; ++j) v[j] = (i0 + j < n) ? cnt[i0 + j] : 0;
    }
#pragma unroll
    for (int j = 0; j < 4; ++j)
      if (i0 + j < n) dinv[i0 + j] = rsqrtf((float)v[j] + 1.0f);
    const int tsum = v[0] + v[1] + v[2] + v[3];
    int x = tsum;
#pragma unroll
    for (int off = 1; off < 64; off <<= 1) {
      int y = __shfl_up(x, off);
      if (lane >= off) x += y;
    }
    if (lane == 63) wsum[wid] = x;
    __syncthreads();
    if (wid == 0) {
      int s = (lane < 16) ? wsum[lane] : 0;
#pragma unroll
      for (int off = 1; off < 16; off <<= 1) {
        int y = __shfl_up(s, off);
        if (lane >= off) s += y;
      }
      if (lane < 16) wsum[lane] = s;
    }
    __syncthreads();
    const int carry = carry_s;
    const int woff = (wid == 0) ? 0 : wsum[wid - 1];
    int run = carry + woff + x - tsum;  // exclusive prefix of first elem
#pragma unroll
    for (int j = 0; j < 4; ++j) {
      if (i0 + j < n) {
        cursor[i0 + j] = run;
        run += v[j];
        rowstart[i0 + j + 1] = run;
      }
    }
    __syncthreads();
    if (t == 1023) carry_s = carry + woff + x;
    __syncthreads();
  }
}

// Fill packed CSR: (src, coef) with coef = dinv[src]*dinv[dst].
__global__ __launch_bounds__(256) void k_fill(const int* __restrict__ src,
                                              const int* __restrict__ dst,
                                              int* __restrict__ cursor,
                                              const float* __restrict__ dinv,
                                              int2* __restrict__ csr, int e) {
  int i = blockIdx.x * 256 + threadIdx.x;
  if (i < e) {
    const int s = src[i], d = dst[i];
    int slot = atomicAdd(&cursor[d], 1);
    csr[slot] = make_int2(s, __float_as_int(dinv[s] * dinv[d]));
  }
}

// ---------------- weight transpose + bf16 split (both layers, one launch) ---
__global__ __launch_bounds__(256) void k_wsplit2(const float* __restrict__ W1,
                                                 unsigned short* __restrict__ W1h,
                                                 unsigned short* __restrict__ W1l,
                                                 const float* __restrict__ W2,
                                                 unsigned short* __restrict__ W2h,
                                                 unsigned short* __restrict__ W2l) {
  constexpr int T1 = F_IN * F_H1;
  constexpr int T2 = F_H1 * F_H2;
  int id = blockIdx.x * 256 + threadIdx.x;
  if (id < T1) {
    int n = id / F_IN, k = id - n * F_IN;
    float f = W1[(size_t)k * F_H1 + n];
    unsigned short h = bf16_rn(f);
    W1h[id] = h;
    W1l[id] = bf16_rn(f - bf16_tof(h));
  } else if (id < T1 + T2) {
    int id2 = id - T1;
    int n = id2 / F_H1, k = id2 - n * F_H1;
    float f = W2[(size_t)k * F_H2 + n];
    unsigned short h = bf16_rn(f);
    W2h[id2] = h;
    W2l[id2] = bf16_rn(f - bf16_tof(h));
  }
}

// ---------------- split-bf16 MFMA GEMM ----------------
// C[M,N] = A[M,K] @ B[K,N], B pre-transposed+split as Bt[N][K] (hi/lo).
// Also writes Cb = bf16(C) if non-null (gather copy for k_agg).
// 128x128 tile, BK=64, 256 threads = 4 waves (2x2), 4x4 frags of 16x16x32.
template <bool A_IS_F32>
__global__ __launch_bounds__(256) void k_mm(const float* __restrict__ Af,
                                            const unsigned short* __restrict__ Ah,
                                            const unsigned short* __restrict__ Al,
                                            const unsigned short* __restrict__ Bth,
                                            const unsigned short* __restrict__ Btl,
                                            float* __restrict__ C,
                                            unsigned short* __restrict__ Cb,
                                            int M, int N, int K) {
  __shared__ unsigned short Ah_s[128 * 64];
  __shared__ unsigned short Al_s[128 * 64];
  __shared__ unsigned short Bh_s[128 * 64];
  __shared__ unsigned short Bl_s[128 * 64];
  const int tid = threadIdx.x;
  const int wid = tid >> 6, lane = tid & 63;
  const int wm = wid >> 1, wn = wid & 1;
  const int lr = lane & 15, lg = lane >> 4;
  const int row0 = blockIdx.x * 128, col0 = blockIdx.y * 128;

  f32x4 acc[4][4] = {};

  for (int k0 = 0; k0 < K; k0 += 64) {
#pragma unroll
    for (int c = 0; c < 4; ++c) {
      const int i8 = c * 256 + tid;
      const int r = i8 >> 3, g = i8 & 7;
      const int gr = row0 + r;
      const int gs = g ^ (r & 7);
      if (A_IS_F32) {
        float4 f0 = make_float4(0.f, 0.f, 0.f, 0.f), f1 = f0;
        if (gr < M) {
          const float* ap = Af + (size_t)gr * K + k0 + g * 8;
          f0 = *(const float4*)ap;
          f1 = *(const float4*)(ap + 4);
        }
        const float fv[8] = {f0.x, f0.y, f0.z, f0.w, f1.x, f1.y, f1.z, f1.w};
        unsigned short hv[8], lv[8];
#pragma unroll
        for (int j = 0; j < 8; ++j) {
          hv[j] = bf16_rn(fv[j]);
          lv[j] = bf16_rn(fv[j] - bf16_tof(hv[j]));
        }
        us4* dh = (us4*)&Ah_s[r * 64 + gs * 8];
        us4* dl = (us4*)&Al_s[r * 64 + gs * 8];
        dh[0] = us4{hv[0], hv[1], hv[2], hv[3]};
        dh[1] = us4{hv[4], hv[5], hv[6], hv[7]};
        dl[0] = us4{lv[0], lv[1], lv[2], lv[3]};
        dl[1] = us4{lv[4], lv[5], lv[6], lv[7]};
      } else {
        short8 h8 = {}, l8 = {};
        if (gr < M) {
          h8 = *(const short8*)&Ah[(size_t)gr * K + k0 + g * 8];
          l8 = *(const short8*)&Al[(size_t)gr * K + k0 + g * 8];
        }
        *(short8*)&Ah_s[r * 64 + gs * 8] = h8;
        *(short8*)&Al_s[r * 64 + gs * 8] = l8;
      }
    }
#pragma unroll
    for (int c = 0; c < 4; ++c) {
      const int i8 = c * 256 + tid;
      const int r = i8 >> 3, g = i8 & 7;
      const int gcol = col0 + r;
      const int gs = g ^ (r & 7);
      *(short8*)&Bh_s[r * 64 + gs * 8] =
          *(const short8*)&Bth[(size_t)gcol * K + k0 + g * 8];
      *(short8*)&Bl_s[r * 64 + gs * 8] =
          *(const short8*)&Btl[(size_t)gcol * K + k0 + g * 8];
    }
    __syncthreads();
#pragma unroll
    for (int kk = 0; kk < 2; ++kk) {
      short8 ah[4], al[4], bh[4], bl[4];
#pragma unroll
      for (int m = 0; m < 4; ++m) {
        const int r = wm * 64 + m * 16 + lr;
        const int g = kk * 4 + lg;
        const int off = r * 64 + (g ^ (r & 7)) * 8;
        ah[m] = *(const short8*)&Ah_s[off];
        al[m] = *(const short8*)&Al_s[off];
      }
#pragma unroll
      for (int n = 0; n < 4; ++n) {
        const int r = wn * 64 + n * 16 + lr;
        const int g = kk * 4 + lg;
        const int off = r * 64 + (g ^ (r & 7)) * 8;
        bh[n] = *(const short8*)&Bh_s[off];
        bl[n] = *(const short8*)&Bl_s[off];
      }
#pragma unroll
      for (int m = 0; m < 4; ++m)
#pragma unroll
        for (int n = 0; n < 4; ++n)
          acc[m][n] = __builtin_amdgcn_mfma_f32_16x16x32_bf16(ah[m], bh[n],
                                                              acc[m][n], 0, 0, 0);
#pragma unroll
      for (int m = 0; m < 4; ++m)
#pragma unroll
        for (int n = 0; n < 4; ++n) {
          acc[m][n] = __builtin_amdgcn_mfma_f32_16x16x32_bf16(ah[m], bl[n],
                                                              acc[m][n], 0, 0, 0);
          acc[m][n] = __builtin_amdgcn_mfma_f32_16x16x32_bf16(al[m], bh[n],
                                                              acc[m][n], 0, 0, 0);
        }
    }
    __syncthreads();
  }
#pragma unroll
  for (int m = 0; m < 4; ++m) {
#pragma unroll
    for (int j = 0; j < 4; ++j) {
      const int row = row0 + wm * 64 + m * 16 + (lane >> 4) * 4 + j;
      if (row < M) {
        const size_t boff = (size_t)row * N + col0 + wn * 64 + (lane & 15);
        float* cp = C + boff;
#pragma unroll
        for (int n = 0; n < 4; ++n) cp[n * 16] = acc[m][n][j];
        if (Cb) {
          unsigned short* cbp = Cb + boff;
#pragma unroll
          for (int n = 0; n < 4; ++n) cbp[n * 16] = bf16_rn(acc[m][n][j]);
        }
      }
    }
  }
}

// ---------------- gather aggregation + fused epilogue ----------------
// One wave per node; 4-wide edge unroll. Neighbors gathered from bf16 copy
// (BF16G) or f32; self-loop term always from f32 h.
// out = leaky_relu(sum_in coef*h[src] + dinv^2*h[node] + bias)
template <int F, bool SPLIT_OUT, bool BF16G>
__global__ __launch_bounds__(256) void k_agg(const float* __restrict__ hf,
                                             const unsigned short* __restrict__ hb,
                                             const int* __restrict__ rowstart,
                                             const int2* __restrict__ csr,
                                             const float* __restrict__ dinv,
                                             const float* __restrict__ bias,
                                             float* __restrict__ outp,
                                             unsigned short* __restrict__ outh,
                                             unsigned short* __restrict__ outl,
                                             int n) {
  constexpr int V = F / 64;
  const int node = (blockIdx.x * 256 + threadIdx.x) >> 6;
  const int lane = threadIdx.x & 63;
  if (node >= n) return;
  const float dn = dinv[node];
  const int e0 = rowstart[node];
  const int cnt = rowstart[node + 1] - e0;
  const int2* cp = csr + e0;
  float acc[V] = {};
  int i = 0;

  auto gather = [&](int s, float f[V]) {
    if constexpr (BF16G) {
      if constexpr (V == 4) {
        const uint2 u = *(const uint2*)(hb + (size_t)s * F + lane * 4);
        f[0] = __uint_as_float(u.x << 16);
        f[1] = __uint_as_float(u.x & 0xffff0000u);
        f[2] = __uint_as_float(u.y << 16);
        f[3] = __uint_as_float(u.y & 0xffff0000u);
      } else {
        const unsigned int u = *(const unsigned int*)(hb + (size_t)s * F + lane * 2);
        f[0] = __uint_as_float(u << 16);
        f[1] = __uint_as_float(u & 0xffff0000u);
      }
    } else {
      if constexpr (V == 4) {
        const float4 v = *(const float4*)(hf + (size_t)s * F + lane * 4);
        f[0] = v.x; f[1] = v.y; f[2] = v.z; f[3] = v.w;
      } else {
        const float2 v = *(const float2*)(hf + (size_t)s * F + lane * 2);
        f[0] = v.x; f[1] = v.y;
      }
    }
  };

  for (; i + 4 <= cnt; i += 4) {
    const int2 p0 = cp[i], p1 = cp[i + 1], p2 = cp[i + 2], p3 = cp[i + 3];
    float f0[V], f1[V], f2[V], f3[V];
    gather(p0.x, f0);
    gather(p1.x, f1);
    gather(p2.x, f2);
    gather(p3.x, f3);
    const float c0 = __int_as_float(p0.y), c1 = __int_as_float(p1.y);
    const float c2 = __int_as_float(p2.y), c3 = __int_as_float(p3.y);
#pragma unroll
    for (int j = 0; j < V; ++j)
      acc[j] += c0 * f0[j] + c1 * f1[j] + c2 * f2[j] + c3 * f3[j];
  }
  for (; i < cnt; ++i) {
    const int2 p = cp[i];
    const float c = __int_as_float(p.y);
    float f[V];
    gather(p.x, f);
#pragma unroll
    for (int j = 0; j < V; ++j) acc[j] += c * f[j];
  }

  const float sc = dn * dn;
  const float* hp = hf + (size_t)node * F + lane * V;
  const float* bp = bias + lane * V;
  float r[V];
#pragma unroll
  for (int j = 0; j < V; ++j) {
    float t = acc[j] + sc * hp[j] + bp[j];
    r[j] = fmaxf(t, 0.2f * t);
  }
  if constexpr (SPLIT_OUT) {
    unsigned short hh[V], ll[V];
#pragma unroll
    for (int j = 0; j < V; ++j) {
      hh[j] = bf16_rn(r[j]);
      ll[j] = bf16_rn(r[j] - bf16_tof(hh[j]));
    }
    if constexpr (V == 4) {
      *(us4*)&outh[(size_t)node * F + lane * 4] = us4{hh[0], hh[1], hh[2], hh[3]};
      *(us4*)&outl[(size_t)node * F + lane * 4] = us4{ll[0], ll[1], ll[2], ll[3]};
    } else {
#pragma unroll
      for (int j = 0; j < V; ++j) {
        outh[(size_t)node * F + lane * V + j] = hh[j];
        outl[(size_t)node * F + lane * V + j] = ll[j];
      }
    }
  } else {
    float* op = outp + (size_t)node * F + lane * V;
    if constexpr (V == 4) {
      *(float4*)op = make_float4(r[0], r[1], r[2], r[3]);
    } else {
      *(float2*)op = make_float2(r[0], r[1]);
    }
  }
}

extern "C" void kernel_launch(void* const* d_in, const int* in_sizes, int n_in,
                              void* d_out, int out_size, void* d_ws, size_t ws_size,
                              hipStream_t stream) {
  const float* X  = (const float*)d_in[0];
  const int*   ei = (const int*)d_in[1];
  const float* W1 = (const float*)d_in[2];
  const float* b1 = (const float*)d_in[3];
  const float* W2 = (const float*)d_in[4];
  const float* b2 = (const float*)d_in[5];
  float* out = (float*)d_out;
  const int* src = ei;
  const int* dst = ei + N_EDGES;

  char* p0 = (char*)d_ws;
  char* p = p0;
  float* h1 = (float*)p;                    p += (size_t)N_NODES * F_H1 * 4;
  unsigned short* z1h = (unsigned short*)p; p += (size_t)N_NODES * F_H1 * 2;
  unsigned short* z1l = (unsigned short*)p; p += (size_t)N_NODES * F_H1 * 2;
  unsigned short* Wt1h = (unsigned short*)p; p += (size_t)F_IN * F_H1 * 2;
  unsigned short* Wt1l = (unsigned short*)p; p += (size_t)F_IN * F_H1 * 2;
  unsigned short* Wt2h = (unsigned short*)p; p += (size_t)F_H1 * F_H2 * 2;
  unsigned short* Wt2l = (unsigned short*)p; p += (size_t)F_H1 * F_H2 * 2;
  float* dinv = (float*)p;                  p += 50048 * 4;
  int* counts = (int*)p;                    p += 50048 * 4;
  int* rowstart = (int*)p;                  p += 50056 * 4;
  int* cursor = (int*)p;                    p += 50048 * 4;
  int2* csr = (int2*)p;                     p += (size_t)N_EDGES * 8;
  unsigned short* h1b = (unsigned short*)p; p += (size_t)N_NODES * F_H1 * 2;
  unsigned short* h2b = h1b;  // h1b dead before mm2 writes h2b (12.8MB < 25.6MB)
  float* h2 = h1;             // h1 dead after agg1
  const bool GB = (size_t)(p - p0) <= ws_size;  // bf16-gather copies fit?

  // --- CSR + normalization ---
  hipMemsetAsync(counts, 0, N_NODES * sizeof(int), stream);
  k_count<<<(N_EDGES + 255) / 256, 256, 0, stream>>>(dst, counts, N_EDGES);
  k_scan<<<1, 1024, 0, stream>>>(counts, rowstart, cursor, dinv, N_NODES);
  k_fill<<<(N_EDGES + 255) / 256, 256, 0, stream>>>(src, dst, cursor, dinv, csr,
                                                    N_EDGES);

  // --- weight prep (both layers, one launch) ---
  k_wsplit2<<<(F_IN * F_H1 + F_H1 * F_H2 + 255) / 256, 256, 0, stream>>>(
      W1, Wt1h, Wt1l, W2, Wt2h, Wt2l);

  // --- layer 1 ---
  dim3 g1((N_NODES + 127) / 128, F_H1 / 128);
  k_mm<true><<<g1, 256, 0, stream>>>(X, nullptr, nullptr, Wt1h, Wt1l, h1,
                                     GB ? h1b : nullptr, N_NODES, F_H1, F_IN);
  if (GB)
    k_agg<F_H1, true, true><<<(N_NODES + 3) / 4, 256, 0, stream>>>(
        h1, h1b, rowstart, csr, dinv, b1, nullptr, z1h, z1l, N_NODES);
  else
    k_agg<F_H1, true, false><<<(N_NODES + 3) / 4, 256, 0, stream>>>(
        h1, nullptr, rowstart, csr, dinv, b1, nullptr, z1h, z1l, N_NODES);

  // --- layer 2 ---
  dim3 g2((N_NODES + 127) / 128, F_H2 / 128);
  k_mm<false><<<g2, 256, 0, stream>>>(nullptr, z1h, z1l, Wt2h, Wt2l, h2,
                                      GB ? h2b : nullptr, N_NODES, F_H2, F_H1);
  if (GB)
    k_agg<F_H2, false, true><<<(N_NODES + 3) / 4, 256, 0, stream>>>(
        h2, h2b, rowstart, csr, dinv, b2, out, nullptr, nullptr, N_NODES);
  else
    k_agg<F_H2, false, false><<<(N_NODES + 3) / 4, 256, 0, stream>>>(
        h2, nullptr, rowstart, csr, dinv, b2, out, nullptr, nullptr, N_NODES);
}